// Round 6
// baseline (471.173 us; speedup 1.0000x reference)
//
#include <hip/hip_runtime.h>
#include <hip/hip_fp16.h>
#include <stdint.h>

typedef uint32_t u32;
typedef uint64_t u64;

#define HWD 512
#define NTX 64            // 64x64 grid of 8x8 tiles
#define NTILES 4096
#define SEG 256           // entries per render segment
#define MAXSEGS 8192      // NTILES + 4N/SEG

__device__ __forceinline__ u32 packh2(float a, float b){
  __half2 h=__floats2half2_rn(a,b);
  return *reinterpret_cast<u32*>(&h);
}
__device__ __forceinline__ float2 unph2(u32 bits){
  __half2 h=*reinterpret_cast<__half2*>(&bits);
  return __half22float2(h);
}

// ---------------- prep: pose-inv + mask-probe + project/shade/pack + pass0 hist + tile counts ----------------
__global__ void __launch_bounds__(256) prep_kernel(const float* __restrict__ pose,
    const float* __restrict__ means, const float* __restrict__ sh,
    const float* __restrict__ opac, const u32* __restrict__ maskw,
    u32* __restrict__ keys, u32* __restrict__ xy, float4* __restrict__ rec0,
    u32* __restrict__ h0, u32* __restrict__ tcnt4, int N, int SB){
  __shared__ float pinvS[12];
  __shared__ u32 hh[256];
  __shared__ u32 mflag;
  int t=threadIdx.x, blk=blockIdx.x;
  int i=blk*256+t;
  hh[t]=0u;
  if (t<64){
    u32 w=maskw[t];
    bool isf=(w==0x3F800000u);
    bool ishi=((w&0xFFFFFF00u)!=0u)&&!isf;
    u64 bf=__ballot((int)isf), bh=__ballot((int)ishi);
    if (t==0) mflag = bh? 1u : (bf? 2u : 0u);   // 1=u8, 2=f32, 0=i32
  }
  if (t==0){
    double a[4][8];
    for(int r=0;r<4;r++)for(int c=0;c<4;c++){a[r][c]=(double)pose[r*4+c];a[r][4+c]=(r==c)?1.0:0.0;}
    for(int c=0;c<4;c++){
      int p=c;double best=fabs(a[c][c]);
      for(int r=c+1;r<4;r++){double v=fabs(a[r][c]);if(v>best){best=v;p=r;}}
      if(p!=c)for(int j=0;j<8;j++){double tt=a[c][j];a[c][j]=a[p][j];a[p][j]=tt;}
      double inv=1.0/a[c][c];
      for(int j=0;j<8;j++)a[c][j]*=inv;
      for(int r=0;r<4;r++)if(r!=c){double f=a[r][c];for(int j=0;j<8;j++)a[r][j]-=f*a[c][j];}
    }
    for(int r=0;r<3;r++)for(int c=0;c<4;c++) pinvS[r*4+c]=(float)a[r][4+c];
  }
  __syncthreads();
  if (i<N){
    u32 f=mflag;
    bool mk;
    if (f==1u)      mk=(((const unsigned char*)maskw)[i]!=0);
    else if (f==2u) mk=(((const float*)maskw)[i]!=0.0f);
    else            mk=(((const int*)maskw)[i]!=0);
    float x=means[3*i], y=means[3*i+1], z=means[3*i+2];
    float cx=pinvS[0]*x+pinvS[1]*y+pinvS[2]*z+pinvS[3];
    float cy=pinvS[4]*x+pinvS[5]*y+pinvS[6]*z+pinvS[7];
    float cz=pinvS[8]*x+pinvS[9]*y+pinvS[10]*z+pinvS[11];
    // exact op order of the reference: ((c*FX)/z) + CX, each fp32-rounded
    float x2d=(cx*409.6f)/cz; x2d=x2d+256.0f;
    float y2d=(cy*409.6f)/cz; y2d=y2d+256.0f;
    bool okx=(x2d>-1.0f)&&(x2d<512.0f);
    bool oky=(y2d>-1.0f)&&(y2d<512.0f);
    bool valid=mk&&okx&&oky;
    int xi=(int)x2d, yi=(int)y2d;
    float alpha= valid? opac[i]:0.0f;
    u32 pk= valid? ((u32)xi|((u32)yi<<16)) : 0xFFFFFFFFu;
    float c0=1.0f/(1.0f+expf(-sh[48*i]));
    float c1=1.0f/(1.0f+expf(-sh[48*i+16]));
    float c2=1.0f/(1.0f+expf(-sh[48*i+32]));
    u32 u=__float_as_uint(cz);
    u32 ou=u^(((u>>31)!=0u)?0xFFFFFFFFu:0x80000000u);
    u32 key=~ou;                    // ascending key == descending z
    keys[i]=key;
    xy[i]=pk;
    rec0[i]=make_float4(__uint_as_float(pk), c0, c1, __uint_as_float(packh2(c2,alpha)));
    atomicAdd(&hh[key&255u],1u);
    if (valid){
      int tx0=max(xi-2,0)>>3, tx1=min(xi+2,HWD-1)>>3;
      int ty0=max(yi-2,0)>>3, ty1=min(yi+2,HWD-1)>>3;
      int sub=i&3;
      for (int ty=ty0;ty<=ty1;ty++)
        for (int tx=tx0;tx<=tx1;tx++)
          atomicAdd(&tcnt4[(u32)((ty*NTX+tx)<<2)|(u32)sub],1u);
    }
  }
  __syncthreads();
  h0[t*SB+blk]=hh[t];
}

// ---------------- tilescan: single block, dual scan -> tileoff, segoff ----------------
__global__ void __launch_bounds__(256) tilescan_kernel(const u32* __restrict__ tcnt4,
    u32* __restrict__ tileoff, u32* __restrict__ segoff){
  __shared__ u32 sA[256], sB[256];
  int t=threadIdx.x;
  u32 pcnt[16], pseg[16];
  u32 sum=0u, ssum=0u;
  #pragma unroll
  for (int k=0;k<16;k++){
    int tile=t*16+k;
    u32 c=tcnt4[tile*4]+tcnt4[tile*4+1]+tcnt4[tile*4+2]+tcnt4[tile*4+3];
    pcnt[k]=sum; pseg[k]=ssum;
    sum+=c; ssum+=(c+SEG-1)/SEG;
  }
  sA[t]=sum; sB[t]=ssum; __syncthreads();
  for (int off=1;off<256;off<<=1){
    u32 xa=(t>=off)?sA[t-off]:0u, xb=(t>=off)?sB[t-off]:0u;
    __syncthreads();
    sA[t]+=xa; sB[t]+=xb;
    __syncthreads();
  }
  u32 b1=(t==0)?0u:sA[t-1], b2=(t==0)?0u:sB[t-1];
  #pragma unroll
  for (int k=0;k<16;k++){
    int tile=t*16+k;
    tileoff[tile]=b1+pcnt[k];
    segoff[tile]=b2+pseg[k];
  }
  if (t==255){ tileoff[NTILES]=sA[255]; segoff[NTILES]=sB[255]; }
}

// ---------------- generic scan: scan1 + scanfix ----------------
__global__ void __launch_bounds__(256) scan1_kernel(const u32* __restrict__ in, u32* __restrict__ out,
                             u32* __restrict__ bsum, int len){
  __shared__ u32 s[256];
  int t=threadIdx.x, blk=blockIdx.x;
  int base=blk*1024 + t*4;
  u32 v0=(base+0<len)?in[base+0]:0u;
  u32 v1=(base+1<len)?in[base+1]:0u;
  u32 v2=(base+2<len)?in[base+2]:0u;
  u32 v3=(base+3<len)?in[base+3]:0u;
  s[t]=v0+v1+v2+v3; __syncthreads();
  for (int off=1;off<256;off<<=1){ u32 x=(t>=off)?s[t-off]:0u; __syncthreads(); s[t]+=x; __syncthreads(); }
  if (t==255) bsum[blk]=s[255];
  u32 run=(t==0)?0u:s[t-1];
  if (base+0<len) out[base+0]=run; run+=v0;
  if (base+1<len) out[base+1]=run; run+=v1;
  if (base+2<len) out[base+2]=run; run+=v2;
  if (base+3<len) out[base+3]=run;
}

__global__ void __launch_bounds__(256) scanfix_kernel(u32* __restrict__ out, const u32* __restrict__ bsum,
                               u32* __restrict__ Mout, int nblk, int len){
  __shared__ u32 red[256];
  int t=threadIdx.x, blk=blockIdx.x;
  u32 s=0u;
  for (int j=t;j<blk;j+=256) s+=bsum[j];
  red[t]=s; __syncthreads();
  for (int off=128;off>0;off>>=1){ if(t<off) red[t]+=red[t+off]; __syncthreads(); }
  u32 base=red[0];
  if (Mout && blk==nblk-1 && t==0) *Mout = base + bsum[blk];
  int i0=blk*1024+t*4;
  #pragma unroll
  for (int k=0;k<4;k++) if (i0+k<len) out[i0+k]+=base;
}

// ---------------- multi-wave stable radix scatter ----------------
// MODE 0: key+payload scatter, fused next-pass histogram
// MODE 1: final z pass — gather/scatter packed records + per-gaussian tile count
// MODE 2: key-only scatter (tile pass A), fused next hist
// MODE 3: key-only scatter (tile pass B, final)
template<int NBITS, int MODE>
__global__ void __launch_bounds__(256) scatter_kernel(
    const u32* __restrict__ kin, const u32* __restrict__ pin,
    u32* __restrict__ kout, u32* __restrict__ pout,
    const u32* __restrict__ histS, u32* __restrict__ hnext,
    const u32* __restrict__ xy, const float4* __restrict__ rec0,
    u32* __restrict__ rxy, float4* __restrict__ rec, u32* __restrict__ ct,
    int shift, int nshift, u32 nmask, int nextlog,
    int n, const u32* __restrict__ nptr, int ipb, int B){
  constexpr int BINS=1<<NBITS;
  __shared__ u32 base[BINS];
  __shared__ u32 wdc[4][BINS];
  int t=threadIdx.x, w=t>>6, lane=t&63, blk=blockIdx.x;
  for (int d=t; d<BINS; d+=256) base[d]=histS[d*B+blk];
  for (int d=t; d<4*BINS; d+=256) ((u32*)wdc)[d]=0u;
  if (nptr) n=(int)*nptr;
  __syncthreads();
  u64 lt=(1ull<<lane)-1ull;
  int nch=ipb>>8;
  for (int c=0;c<nch;c++){
    int i=blk*ipb + c*256 + t;
    bool live=(i<n);
    u32 key=live?kin[i]:0u;
    u32 pay=0u;
    if constexpr (MODE==0){ pay = pin? (live?pin[i]:0u) : (u32)i; }
    else if constexpr (MODE==1){ pay = live?pin[i]:0u; }
    u32 d=(key>>shift)&(u32)(BINS-1);
    u64 m=~0ull;
    #pragma unroll
    for (int b=0;b<NBITS;b++){ u64 bal=__ballot((int)((d>>b)&1u)); m &= ((d>>b)&1u)?bal:~bal; }
    m &= __ballot((int)live);
    u32 rank=(u32)__popcll(m&lt);
    u32 cnt=(u32)__popcll(m);
    if (live && rank==0u) wdc[w][d]=cnt;
    __syncthreads();
    if (live){
      u32 off=base[d]+rank;
      for (int w2=0;w2<w;w2++) off+=wdc[w2][d];
      if constexpr (MODE==0){
        kout[off]=key; pout[off]=pay;
        atomicAdd(&hnext[((key>>nshift)&nmask)*(u32)B + (off>>nextlog)],1u);
      } else if constexpr (MODE==1){
        u32 pk=xy[pay];
        rxy[off]=pk;
        rec[off]=rec0[pay];
        u32 c2=0u;
        if (pk!=0xFFFFFFFFu){
          int xi=(int)(pk&0xFFFFu), yi=(int)(pk>>16);
          int tx0=max(xi-2,0)>>3, tx1=min(xi+2,HWD-1)>>3;
          int ty0=max(yi-2,0)>>3, ty1=min(yi+2,HWD-1)>>3;
          c2=(u32)((tx1-tx0+1)*(ty1-ty0+1));
        }
        ct[off]=c2;
      } else if constexpr (MODE==2){
        kout[off]=key;
        atomicAdd(&hnext[((key>>nshift)&nmask)*(u32)B + (off>>nextlog)],1u);
      } else {
        kout[off]=key;
      }
    }
    __syncthreads();
    for (int d2=t; d2<BINS; d2+=256){
      base[d2]+=wdc[0][d2]+wdc[1][d2]+wdc[2][d2]+wdc[3][d2];
      wdc[0][d2]=0u; wdc[1][d2]=0u; wdc[2][d2]=0u; wdc[3][d2]=0u;
    }
    __syncthreads();
  }
}

// ---------------- emit: sequential per sorted gaussian (stable in p) + fused tile-pass-A hist ----------------
__global__ void __launch_bounds__(256) emit_kernel(const u32* __restrict__ rxy,
    const u32* __restrict__ coffs, u32* __restrict__ entries, u32* __restrict__ hT0,
    int N, int BT, int Llog){
  int p=blockIdx.x*256+threadIdx.x; if(p>=N) return;
  u32 pk=rxy[p]; if(pk==0xFFFFFFFFu) return;
  int xi=(int)(pk&0xFFFFu), yi=(int)(pk>>16);
  int tx0=max(xi-2,0)>>3, tx1=min(xi+2,HWD-1)>>3;
  int ty0=max(yi-2,0)>>3, ty1=min(yi+2,HWD-1)>>3;
  u32 o=coffs[p];
  for (int ty=ty0;ty<=ty1;ty++)
    for (int tx=tx0;tx<=tx1;tx++){
      u32 tile=(u32)(ty*NTX+tx);
      entries[o]=(tile<<18)|(u32)p;
      atomicAdd(&hT0[(tile&255u)*(u32)BT + (o>>Llog)],1u);
      o++;
    }
}

// ---------------- render phase 1: one wave per 256-entry segment -> per-pixel affine (T,C) ----------------
__global__ void __launch_bounds__(64) renderseg_kernel(const u32* __restrict__ segoff,
    const u32* __restrict__ tileoff, const u32* __restrict__ sidE,
    const float4* __restrict__ rec, float4* __restrict__ pt){
  int lane=threadIdx.x;
  u32 k=blockIdx.x;
  if (k>=segoff[NTILES]) return;
  int lo=0, hi=NTILES-1;
  while (lo<hi){ int mid=(lo+hi+1)>>1; if (segoff[mid]<=k) lo=mid; else hi=mid-1; }
  int tile=lo;
  u32 st=tileoff[tile], en=tileoff[tile+1];
  int s0=(int)st+(int)(k-segoff[tile])*SEG;
  int s1=min(s0+SEG,(int)en);
  int px=(tile&(NTX-1))*8+(lane&7), py=(tile/NTX)*8+(lane>>3);
  __shared__ float4 sac[64];
  float T=1.0f, cr=0.0f, cg=0.0f, cb=0.0f;
  for (int base=s0;base<s1;base+=64){
    int i=base+lane;
    if (i<s1) sac[lane]=rec[sidE[i]&0x3FFFFu];
    __syncthreads();
    int cnt=min(64,s1-base);
    int j=0;
    for (;j+4<=cnt;j+=4){
      #pragma unroll
      for (int q=0;q<4;q++){
        float4 R=sac[j+q];
        u32 pk=__float_as_uint(R.x);
        int dx=px-(int)(pk&0xFFFFu);
        int dy=py-(int)(pk>>16);
        int r2=dx*dx+dy*dy;
        float2 ca=unph2(__float_as_uint(R.w));   // (c2, alpha)
        float aw=ca.y*exp2f(-0.72134752f*(float)r2);
        aw=(r2<=8)?aw:0.0f;
        float om=1.0f-aw;
        T*=om;
        cr=om*cr+aw*R.y;
        cg=om*cg+aw*R.z;
        cb=om*cb+aw*ca.x;
      }
    }
    for (;j<cnt;j++){
      float4 R=sac[j];
      u32 pk=__float_as_uint(R.x);
      int dx=px-(int)(pk&0xFFFFu);
      int dy=py-(int)(pk>>16);
      int r2=dx*dx+dy*dy;
      float2 ca=unph2(__float_as_uint(R.w));
      float aw=ca.y*exp2f(-0.72134752f*(float)r2);
      aw=(r2<=8)?aw:0.0f;
      float om=1.0f-aw;
      T*=om;
      cr=om*cr+aw*R.y;
      cg=om*cg+aw*R.z;
      cb=om*cb+aw*ca.x;
    }
    __syncthreads();
  }
  pt[(u32)k*64u+(u32)lane]=make_float4(T,cr,cg,cb);
}

// ---------------- render phase 2: compose segment maps in depth order ----------------
__global__ void __launch_bounds__(64) combine_kernel(const u32* __restrict__ segoff,
    const float4* __restrict__ pt, float* __restrict__ out){
  int tile=blockIdx.x, lane=threadIdx.x;
  u32 a=segoff[tile], b=segoff[tile+1];
  float cr=0.0f,cg=0.0f,cb=0.0f;
  for (u32 s=a;s<b;s++){
    float4 P=pt[s*64u+(u32)lane];
    cr=P.x*cr+P.y; cg=P.x*cg+P.z; cb=P.x*cb+P.w;
  }
  int px=(tile&(NTX-1))*8+(lane&7), py=(tile/NTX)*8+(lane>>3);
  int o=py*HWD+px;
  out[o]=cr; out[HWD*HWD+o]=cg; out[2*HWD*HWD+o]=cb;
}

// ---------------- launcher ----------------
extern "C" void kernel_launch(void* const* d_in, const int* in_sizes, int n_in,
                              void* d_out, int out_size, void* d_ws, size_t ws_size,
                              hipStream_t stream){
  const float* pose=(const float*)d_in[0];
  const float* means=(const float*)d_in[1];
  const float* sh=(const float*)d_in[2];
  const float* opac=(const float*)d_in[3];
  const u32* maskw=(const u32*)d_in[4];
  int N=in_sizes[4];
  if (N<=0) return;
  (void)n_in; (void)out_size; (void)ws_size;

  int SB=(N+255)/256;                    // z-sort blocks (ipb=256)
  const int BT=1024;                     // tile-sort blocks
  int Llog=8; while ((BT<<Llog) < 4*N) Llog++;   // ipbT = 1<<Llog per block
  int ipbT=1<<Llog;

  char* ws=(char*)d_ws; size_t off=0;
  auto alloc=[&](size_t b)->void*{ void* p=(void*)(ws+off); off=(off+b+255)&~(size_t)255; return p; };
  u32* keysA=(u32*)alloc(4ull*N);
  u32* keysB=(u32*)alloc(4ull*N);
  u32* idxA =(u32*)alloc(4ull*N);
  u32* idxB =(u32*)alloc(4ull*N);
  u32* xy   =(u32*)alloc(4ull*N);
  float4* rec0=(float4*)alloc(16ull*N);
  u32* rxy  =(u32*)alloc(4ull*N);
  float4* rec=(float4*)alloc(16ull*N);
  u32* ct   =(u32*)alloc(4ull*N);
  u32* entriesA=(u32*)alloc(4ull*4*N);   // also final sidE
  u32* entriesB=(u32*)alloc(4ull*4*N);
  u32* h0=(u32*)alloc(1024ull*SB);
  char* zstart=ws+off;
  u32* h1=(u32*)alloc(1024ull*SB);
  u32* h2=(u32*)alloc(1024ull*SB);
  u32* h3=(u32*)alloc(1024ull*SB);
  u32* hT0=(u32*)alloc(4ull*256*BT);
  u32* hT1=(u32*)alloc(4ull*16*BT);
  u32* tcnt4=(u32*)alloc(4ull*4*NTILES);
  size_t zbytes=(size_t)((ws+off)-zstart);
  u32* tileoff=(u32*)alloc(4ull*(NTILES+1));
  u32* segoff =(u32*)alloc(4ull*(NTILES+1));
  u32* bsum=(u32*)alloc(4ull*4096);
  u32* Mptr=(u32*)alloc(256);
  float4* pt=(float4*)alloc(16ull*64*MAXSEGS);   // 8 MB

  hipMemsetAsync(zstart,0,zbytes,stream);
  prep_kernel<<<SB,256,0,stream>>>(pose,means,sh,opac,maskw,keysA,xy,rec0,h0,tcnt4,N,SB);
  tilescan_kernel<<<1,256,0,stream>>>(tcnt4,tileoff,segoff);

  int hlen=256*SB, sbh=(hlen+1023)/1024;
  // z pass 0
  scan1_kernel  <<<sbh,256,0,stream>>>(h0,h0,bsum,hlen);
  scanfix_kernel<<<sbh,256,0,stream>>>(h0,bsum,nullptr,sbh,hlen);
  scatter_kernel<8,0><<<SB,256,0,stream>>>(keysA,nullptr,keysB,idxB,h0,h1,
      nullptr,nullptr,nullptr,nullptr,nullptr, 0,8,255u,8, N,nullptr,256,SB);
  // z pass 1
  scan1_kernel  <<<sbh,256,0,stream>>>(h1,h1,bsum,hlen);
  scanfix_kernel<<<sbh,256,0,stream>>>(h1,bsum,nullptr,sbh,hlen);
  scatter_kernel<8,0><<<SB,256,0,stream>>>(keysB,idxB,keysA,idxA,h1,h2,
      nullptr,nullptr,nullptr,nullptr,nullptr, 8,16,255u,8, N,nullptr,256,SB);
  // z pass 2
  scan1_kernel  <<<sbh,256,0,stream>>>(h2,h2,bsum,hlen);
  scanfix_kernel<<<sbh,256,0,stream>>>(h2,bsum,nullptr,sbh,hlen);
  scatter_kernel<8,0><<<SB,256,0,stream>>>(keysA,idxA,keysB,idxB,h2,h3,
      nullptr,nullptr,nullptr,nullptr,nullptr, 16,24,255u,8, N,nullptr,256,SB);
  // z pass 3 (final: gather records into sorted order + tile counts)
  scan1_kernel  <<<sbh,256,0,stream>>>(h3,h3,bsum,hlen);
  scanfix_kernel<<<sbh,256,0,stream>>>(h3,bsum,nullptr,sbh,hlen);
  scatter_kernel<8,1><<<SB,256,0,stream>>>(keysB,idxB,nullptr,nullptr,h3,nullptr,
      xy,rec0,rxy,rec,ct, 24,0,0u,0, N,nullptr,256,SB);

  // entry offsets per sorted gaussian + M
  int sbn=(N+1023)/1024;
  scan1_kernel  <<<sbn,256,0,stream>>>(ct,ct,bsum,N);
  scanfix_kernel<<<sbn,256,0,stream>>>(ct,bsum,Mptr,sbn,N);
  // emit entries (stable in p) + fused tile-pass-A hist
  emit_kernel<<<SB,256,0,stream>>>(rxy,ct,entriesA,hT0,N,BT,Llog);
  // tile pass A (low 8 bits of tile)
  int thlen=256*BT, sbt=(thlen+1023)/1024;
  scan1_kernel  <<<sbt,256,0,stream>>>(hT0,hT0,bsum,thlen);
  scanfix_kernel<<<sbt,256,0,stream>>>(hT0,bsum,nullptr,sbt,thlen);
  scatter_kernel<8,2><<<BT,256,0,stream>>>(entriesA,nullptr,entriesB,nullptr,hT0,hT1,
      nullptr,nullptr,nullptr,nullptr,nullptr, 18,26,15u,Llog, 0,Mptr,ipbT,BT);
  // tile pass B (high 4 bits of tile)
  int t1len=16*BT, sb1=(t1len+1023)/1024;
  scan1_kernel  <<<sb1,256,0,stream>>>(hT1,hT1,bsum,t1len);
  scanfix_kernel<<<sb1,256,0,stream>>>(hT1,bsum,nullptr,sb1,t1len);
  scatter_kernel<4,3><<<BT,256,0,stream>>>(entriesB,nullptr,entriesA,nullptr,hT1,nullptr,
      nullptr,nullptr,nullptr,nullptr,nullptr, 26,0,0u,0, 0,Mptr,ipbT,BT);

  // render
  renderseg_kernel<<<MAXSEGS,64,0,stream>>>(segoff,tileoff,entriesA,rec,pt);
  combine_kernel<<<NTILES,64,0,stream>>>(segoff,pt,(float*)d_out);
}

// Round 7
// 203.616 us; speedup vs baseline: 2.3140x; 2.3140x over previous
//
#include <hip/hip_runtime.h>
#include <hip/hip_fp16.h>
#include <stdint.h>

typedef uint32_t u32;
typedef uint64_t u64;

#define HWD 512
#define NTX 64            // 64x64 grid of 8x8 tiles
#define NTILES 4096
#define SEG 256           // entries per render segment
#define MAXSEGS 8192      // NTILES + 4N/SEG

__device__ __forceinline__ u32 packh2(float a, float b){
  __half2 h=__floats2half2_rn(a,b);
  return *reinterpret_cast<u32*>(&h);
}
__device__ __forceinline__ float2 unph2(u32 bits){
  __half2 h=*reinterpret_cast<__half2*>(&bits);
  return __half22float2(h);
}

// ---------------- prep: pose-inv + mask-probe + project/shade/pack + pass0 hist ----------------
// NO global atomics (tcnt4 removed — tile offsets recovered post-sort by tbound_kernel).
__global__ void __launch_bounds__(256) prep_kernel(const float* __restrict__ pose,
    const float* __restrict__ means, const float* __restrict__ sh,
    const float* __restrict__ opac, const u32* __restrict__ maskw,
    u32* __restrict__ keys, u32* __restrict__ xy, float4* __restrict__ rec0,
    u32* __restrict__ h0, int N, int SB){
  __shared__ float pinvS[12];
  __shared__ u32 hh[256];
  __shared__ u32 mflag;
  int t=threadIdx.x, blk=blockIdx.x;
  int i=blk*256+t;
  hh[t]=0u;
  if (t<64){
    // mask dtype probe on first 64 words (uniform across blocks -> uniform decision)
    u32 w=maskw[t];
    bool isf=(w==0x3F800000u);
    bool ishi=((w&0xFFFFFF00u)!=0u)&&!isf;
    u64 bf=__ballot((int)isf), bh=__ballot((int)ishi);
    if (t==0) mflag = bh? 1u : (bf? 2u : 0u);   // 1=u8, 2=f32, 0=i32
  }
  if (t==0){
    double a[4][8];
    for(int r=0;r<4;r++)for(int c=0;c<4;c++){a[r][c]=(double)pose[r*4+c];a[r][4+c]=(r==c)?1.0:0.0;}
    for(int c=0;c<4;c++){
      int p=c;double best=fabs(a[c][c]);
      for(int r=c+1;r<4;r++){double v=fabs(a[r][c]);if(v>best){best=v;p=r;}}
      if(p!=c)for(int j=0;j<8;j++){double tt=a[c][j];a[c][j]=a[p][j];a[p][j]=tt;}
      double inv=1.0/a[c][c];
      for(int j=0;j<8;j++)a[c][j]*=inv;
      for(int r=0;r<4;r++)if(r!=c){double f=a[r][c];for(int j=0;j<8;j++)a[r][j]-=f*a[c][j];}
    }
    for(int r=0;r<3;r++)for(int c=0;c<4;c++) pinvS[r*4+c]=(float)a[r][4+c];
  }
  __syncthreads();
  if (i<N){
    u32 f=mflag;
    bool mk;
    if (f==1u)      mk=(((const unsigned char*)maskw)[i]!=0);
    else if (f==2u) mk=(((const float*)maskw)[i]!=0.0f);
    else            mk=(((const int*)maskw)[i]!=0);
    float x=means[3*i], y=means[3*i+1], z=means[3*i+2];
    float cx=pinvS[0]*x+pinvS[1]*y+pinvS[2]*z+pinvS[3];
    float cy=pinvS[4]*x+pinvS[5]*y+pinvS[6]*z+pinvS[7];
    float cz=pinvS[8]*x+pinvS[9]*y+pinvS[10]*z+pinvS[11];
    // exact op order of the reference: ((c*FX)/z) + CX, each fp32-rounded
    float x2d=(cx*409.6f)/cz; x2d=x2d+256.0f;
    float y2d=(cy*409.6f)/cz; y2d=y2d+256.0f;
    bool okx=(x2d>-1.0f)&&(x2d<512.0f);
    bool oky=(y2d>-1.0f)&&(y2d<512.0f);
    bool valid=mk&&okx&&oky;
    int xi=(int)x2d, yi=(int)y2d;
    float alpha= valid? opac[i]:0.0f;
    u32 pk= valid? ((u32)xi|((u32)yi<<16)) : 0xFFFFFFFFu;
    float c0=1.0f/(1.0f+expf(-sh[48*i]));
    float c1=1.0f/(1.0f+expf(-sh[48*i+16]));
    float c2=1.0f/(1.0f+expf(-sh[48*i+32]));
    u32 u=__float_as_uint(cz);
    u32 ou=u^(((u>>31)!=0u)?0xFFFFFFFFu:0x80000000u);
    u32 key=~ou;                    // ascending key == descending z
    keys[i]=key;
    xy[i]=pk;
    rec0[i]=make_float4(__uint_as_float(pk), c0, c1, __uint_as_float(packh2(c2,alpha)));
    atomicAdd(&hh[key&255u],1u);    // LDS only
  }
  __syncthreads();
  h0[t*SB+blk]=hh[t];
}

// ---------------- generic scan: scan1 + scanfix ----------------
__global__ void __launch_bounds__(256) scan1_kernel(const u32* __restrict__ in, u32* __restrict__ out,
                             u32* __restrict__ bsum, int len){
  __shared__ u32 s[256];
  int t=threadIdx.x, blk=blockIdx.x;
  int base=blk*1024 + t*4;
  u32 v0=(base+0<len)?in[base+0]:0u;
  u32 v1=(base+1<len)?in[base+1]:0u;
  u32 v2=(base+2<len)?in[base+2]:0u;
  u32 v3=(base+3<len)?in[base+3]:0u;
  s[t]=v0+v1+v2+v3; __syncthreads();
  for (int off=1;off<256;off<<=1){ u32 x=(t>=off)?s[t-off]:0u; __syncthreads(); s[t]+=x; __syncthreads(); }
  if (t==255) bsum[blk]=s[255];
  u32 run=(t==0)?0u:s[t-1];
  if (base+0<len) out[base+0]=run; run+=v0;
  if (base+1<len) out[base+1]=run; run+=v1;
  if (base+2<len) out[base+2]=run; run+=v2;
  if (base+3<len) out[base+3]=run;
}

__global__ void __launch_bounds__(256) scanfix_kernel(u32* __restrict__ out, const u32* __restrict__ bsum,
                               u32* __restrict__ Mout, int nblk, int len){
  __shared__ u32 red[256];
  int t=threadIdx.x, blk=blockIdx.x;
  u32 s=0u;
  for (int j=t;j<blk;j+=256) s+=bsum[j];
  red[t]=s; __syncthreads();
  for (int off=128;off>0;off>>=1){ if(t<off) red[t]+=red[t+off]; __syncthreads(); }
  u32 base=red[0];
  if (Mout && blk==nblk-1 && t==0) *Mout = base + bsum[blk];
  int i0=blk*1024+t*4;
  #pragma unroll
  for (int k=0;k<4;k++) if (i0+k<len) out[i0+k]+=base;
}

// ---------------- per-block histogram (LDS atomics only, transposed write) ----------------
template<int NBITS>
__global__ void __launch_bounds__(256) hist_kernel(const u32* __restrict__ keys,
    u32* __restrict__ h, int shift, int n, const u32* __restrict__ nptr, int ipb, int B){
  constexpr int BINS=1<<NBITS;
  __shared__ u32 hh[BINS];
  int t=threadIdx.x, blk=blockIdx.x;
  for (int d=t; d<BINS; d+=256) hh[d]=0u;
  if (nptr) n=(int)*nptr;
  __syncthreads();
  int base=blk*ipb;
  for (int k=0;k<ipb;k+=256){
    int i=base+k+t;
    if (i<n) atomicAdd(&hh[(keys[i]>>shift)&(u32)(BINS-1)],1u);
  }
  __syncthreads();
  for (int d=t; d<BINS; d+=256) h[d*B+blk]=hh[d];
}

// ---------------- multi-wave stable radix scatter (no global atomics) ----------------
// MODE 0: key+payload scatter
// MODE 1: final z pass — gather packed records into sorted order + per-gaussian tile count
// MODE 2: key-only scatter
template<int NBITS, int MODE>
__global__ void __launch_bounds__(256) scatter_kernel(
    const u32* __restrict__ kin, const u32* __restrict__ pin,
    u32* __restrict__ kout, u32* __restrict__ pout,
    const u32* __restrict__ histS,
    const u32* __restrict__ xy, const float4* __restrict__ rec0,
    u32* __restrict__ rxy, float4* __restrict__ rec, u32* __restrict__ ct,
    int shift, int n, const u32* __restrict__ nptr, int ipb, int B){
  constexpr int BINS=1<<NBITS;
  __shared__ u32 base[BINS];
  __shared__ u32 wdc[4][BINS];
  int t=threadIdx.x, w=t>>6, lane=t&63, blk=blockIdx.x;
  for (int d=t; d<BINS; d+=256) base[d]=histS[d*B+blk];
  for (int d=t; d<4*BINS; d+=256) ((u32*)wdc)[d]=0u;
  if (nptr) n=(int)*nptr;
  __syncthreads();
  u64 lt=(1ull<<lane)-1ull;
  int nch=ipb>>8;
  for (int c=0;c<nch;c++){
    int i=blk*ipb + c*256 + t;
    bool live=(i<n);
    u32 key=live?kin[i]:0u;
    u32 pay=0u;
    if constexpr (MODE==0){ pay = pin? (live?pin[i]:0u) : (u32)i; }
    else if constexpr (MODE==1){ pay = live?pin[i]:0u; }
    u32 d=(key>>shift)&(u32)(BINS-1);
    u64 m=~0ull;
    #pragma unroll
    for (int b=0;b<NBITS;b++){ u64 bal=__ballot((int)((d>>b)&1u)); m &= ((d>>b)&1u)?bal:~bal; }
    m &= __ballot((int)live);
    u32 rank=(u32)__popcll(m&lt);
    u32 cnt=(u32)__popcll(m);
    if (live && rank==0u) wdc[w][d]=cnt;
    __syncthreads();
    if (live){
      u32 off=base[d]+rank;
      for (int w2=0;w2<w;w2++) off+=wdc[w2][d];
      if constexpr (MODE==0){
        kout[off]=key; pout[off]=pay;
      } else if constexpr (MODE==1){
        u32 pk=xy[pay];
        rxy[off]=pk;
        rec[off]=rec0[pay];
        u32 c2=0u;
        if (pk!=0xFFFFFFFFu){
          int xi=(int)(pk&0xFFFFu), yi=(int)(pk>>16);
          int tx0=max(xi-2,0)>>3, tx1=min(xi+2,HWD-1)>>3;
          int ty0=max(yi-2,0)>>3, ty1=min(yi+2,HWD-1)>>3;
          c2=(u32)((tx1-tx0+1)*(ty1-ty0+1));
        }
        ct[off]=c2;
      } else {
        kout[off]=key;
      }
    }
    __syncthreads();
    for (int d2=t; d2<BINS; d2+=256){
      base[d2]+=wdc[0][d2]+wdc[1][d2]+wdc[2][d2]+wdc[3][d2];
      wdc[0][d2]=0u; wdc[1][d2]=0u; wdc[2][d2]=0u; wdc[3][d2]=0u;
    }
    __syncthreads();
  }
}

// ---------------- emit: entries at scanned offsets, p-ascending (stable baseline) ----------------
__global__ void __launch_bounds__(256) emit_kernel(const u32* __restrict__ rxy,
    const u32* __restrict__ coffs, u32* __restrict__ entries, int N){
  int p=blockIdx.x*256+threadIdx.x; if(p>=N) return;
  u32 pk=rxy[p]; if(pk==0xFFFFFFFFu) return;
  int xi=(int)(pk&0xFFFFu), yi=(int)(pk>>16);
  int tx0=max(xi-2,0)>>3, tx1=min(xi+2,HWD-1)>>3;
  int ty0=max(yi-2,0)>>3, ty1=min(yi+2,HWD-1)>>3;
  u32 o=coffs[p];
  for (int ty=ty0;ty<=ty1;ty++)
    for (int tx=tx0;tx<=tx1;tx++){
      entries[o]=((u32)(ty*NTX+tx)<<18)|(u32)p;
      o++;
    }
}

// ---------------- tile boundaries from sorted entries ----------------
__global__ void __launch_bounds__(256) tbound_kernel(const u32* __restrict__ entries,
    const u32* __restrict__ Mptr, u32* __restrict__ tileoff){
  u32 M=*Mptr;
  u32 i=(u32)blockIdx.x*256u+(u32)threadIdx.x;
  if (i>M) return;
  if (i==M){
    int tlast=(M==0u)? -1 : (int)(entries[M-1]>>18);
    for (int tt=tlast+1; tt<=NTILES; tt++) tileoff[tt]=M;
    return;
  }
  int ti=(int)(entries[i]>>18);
  int tp=(i==0u)? -1 : (int)(entries[i-1]>>18);
  for (int tt=tp+1; tt<=ti; tt++) tileoff[tt]=i;
}

// ---------------- segment table from tileoff (single block) ----------------
__global__ void __launch_bounds__(256) segscan_kernel(const u32* __restrict__ tileoff,
    u32* __restrict__ segoff){
  __shared__ u32 s[256];
  int t=threadIdx.x;
  u32 pseg[16]; u32 ssum=0u;
  #pragma unroll
  for (int k=0;k<16;k++){
    int tile=t*16+k;
    u32 cnt=tileoff[tile+1]-tileoff[tile];
    pseg[k]=ssum; ssum+=(cnt+SEG-1)/SEG;
  }
  s[t]=ssum; __syncthreads();
  for (int off=1;off<256;off<<=1){ u32 x=(t>=off)?s[t-off]:0u; __syncthreads(); s[t]+=x; __syncthreads(); }
  u32 b2=(t==0)?0u:s[t-1];
  #pragma unroll
  for (int k=0;k<16;k++) segoff[t*16+k]=b2+pseg[k];
  if (t==255) segoff[NTILES]=s[255];
}

// ---------------- render phase 1: one wave per 256-entry segment -> per-pixel affine (T,C) ----------------
__global__ void __launch_bounds__(64) renderseg_kernel(const u32* __restrict__ segoff,
    const u32* __restrict__ tileoff, const u32* __restrict__ sidE,
    const float4* __restrict__ rec, float4* __restrict__ pt){
  int lane=threadIdx.x;
  u32 k=blockIdx.x;
  if (k>=segoff[NTILES]) return;
  int lo=0, hi=NTILES-1;
  while (lo<hi){ int mid=(lo+hi+1)>>1; if (segoff[mid]<=k) lo=mid; else hi=mid-1; }
  int tile=lo;
  u32 st=tileoff[tile], en=tileoff[tile+1];
  int s0=(int)st+(int)(k-segoff[tile])*SEG;
  int s1=min(s0+SEG,(int)en);
  int px=(tile&(NTX-1))*8+(lane&7), py=(tile/NTX)*8+(lane>>3);
  __shared__ float4 sac[64];
  float T=1.0f, cr=0.0f, cg=0.0f, cb=0.0f;
  for (int base=s0;base<s1;base+=64){
    int i=base+lane;
    if (i<s1) sac[lane]=rec[sidE[i]&0x3FFFFu];
    __syncthreads();
    int cnt=min(64,s1-base);
    int j=0;
    for (;j+4<=cnt;j+=4){
      #pragma unroll
      for (int q=0;q<4;q++){
        float4 R=sac[j+q];
        u32 pk=__float_as_uint(R.x);
        int dx=px-(int)(pk&0xFFFFu);
        int dy=py-(int)(pk>>16);
        int r2=dx*dx+dy*dy;
        float2 ca=unph2(__float_as_uint(R.w));   // (c2, alpha)
        float aw=ca.y*exp2f(-0.72134752f*(float)r2);
        aw=(r2<=8)?aw:0.0f;
        float om=1.0f-aw;
        T*=om;
        cr=om*cr+aw*R.y;
        cg=om*cg+aw*R.z;
        cb=om*cb+aw*ca.x;
      }
    }
    for (;j<cnt;j++){
      float4 R=sac[j];
      u32 pk=__float_as_uint(R.x);
      int dx=px-(int)(pk&0xFFFFu);
      int dy=py-(int)(pk>>16);
      int r2=dx*dx+dy*dy;
      float2 ca=unph2(__float_as_uint(R.w));
      float aw=ca.y*exp2f(-0.72134752f*(float)r2);
      aw=(r2<=8)?aw:0.0f;
      float om=1.0f-aw;
      T*=om;
      cr=om*cr+aw*R.y;
      cg=om*cg+aw*R.z;
      cb=om*cb+aw*ca.x;
    }
    __syncthreads();
  }
  pt[(u32)k*64u+(u32)lane]=make_float4(T,cr,cg,cb);
}

// ---------------- render phase 2: compose segment maps in depth order ----------------
__global__ void __launch_bounds__(64) combine_kernel(const u32* __restrict__ segoff,
    const float4* __restrict__ pt, float* __restrict__ out){
  int tile=blockIdx.x, lane=threadIdx.x;
  u32 a=segoff[tile], b=segoff[tile+1];
  float cr=0.0f,cg=0.0f,cb=0.0f;
  for (u32 s=a;s<b;s++){
    float4 P=pt[s*64u+(u32)lane];
    cr=P.x*cr+P.y; cg=P.x*cg+P.z; cb=P.x*cb+P.w;
  }
  int px=(tile&(NTX-1))*8+(lane&7), py=(tile/NTX)*8+(lane>>3);
  int o=py*HWD+px;
  out[o]=cr; out[HWD*HWD+o]=cg; out[2*HWD*HWD+o]=cb;
}

// ---------------- launcher ----------------
extern "C" void kernel_launch(void* const* d_in, const int* in_sizes, int n_in,
                              void* d_out, int out_size, void* d_ws, size_t ws_size,
                              hipStream_t stream){
  const float* pose=(const float*)d_in[0];
  const float* means=(const float*)d_in[1];
  const float* sh=(const float*)d_in[2];
  const float* opac=(const float*)d_in[3];
  const u32* maskw=(const u32*)d_in[4];
  int N=in_sizes[4];
  if (N<=0) return;
  (void)n_in; (void)out_size; (void)ws_size;

  int SB=(N+255)/256;                    // z-sort blocks (ipb=256)
  const int BT=1024;                     // tile-sort blocks
  int Llog=8; while ((BT<<Llog) < 4*N) Llog++;
  int ipbT=1<<Llog;

  char* ws=(char*)d_ws; size_t off=0;
  auto alloc=[&](size_t b)->void*{ void* p=(void*)(ws+off); off=(off+b+255)&~(size_t)255; return p; };
  u32* keysA=(u32*)alloc(4ull*N);
  u32* keysB=(u32*)alloc(4ull*N);
  u32* idxA =(u32*)alloc(4ull*N);
  u32* idxB =(u32*)alloc(4ull*N);
  u32* xy   =(u32*)alloc(4ull*N);
  float4* rec0=(float4*)alloc(16ull*N);
  u32* rxy  =(u32*)alloc(4ull*N);
  float4* rec=(float4*)alloc(16ull*N);
  u32* ct   =(u32*)alloc(4ull*N);
  u32* entriesA=(u32*)alloc(4ull*4*N);   // also final sorted entries
  u32* entriesB=(u32*)alloc(4ull*4*N);
  u32* h0=(u32*)alloc(1024ull*SB);
  u32* h1=(u32*)alloc(1024ull*SB);
  u32* h2=(u32*)alloc(1024ull*SB);
  u32* h3=(u32*)alloc(1024ull*SB);
  u32* hT0=(u32*)alloc(4ull*256*BT);
  u32* hT1=(u32*)alloc(4ull*16*BT);
  u32* tileoff=(u32*)alloc(4ull*(NTILES+1));
  u32* segoff =(u32*)alloc(4ull*(NTILES+1));
  u32* bsum=(u32*)alloc(4ull*4096);
  u32* Mptr=(u32*)alloc(256);
  float4* pt=(float4*)alloc(16ull*64*MAXSEGS);   // 8 MB

  hipMemsetAsync(tileoff,0,4ull*(NTILES+1),stream);
  prep_kernel<<<SB,256,0,stream>>>(pose,means,sh,opac,maskw,keysA,xy,rec0,h0,N,SB);

  int hlen=256*SB, sbh=(hlen+1023)/1024;
  // z pass 0
  scan1_kernel  <<<sbh,256,0,stream>>>(h0,h0,bsum,hlen);
  scanfix_kernel<<<sbh,256,0,stream>>>(h0,bsum,nullptr,sbh,hlen);
  scatter_kernel<8,0><<<SB,256,0,stream>>>(keysA,nullptr,keysB,idxB,h0,
      nullptr,nullptr,nullptr,nullptr,nullptr, 0, N,nullptr,256,SB);
  // z pass 1
  hist_kernel<8><<<SB,256,0,stream>>>(keysB,h1,8,N,nullptr,256,SB);
  scan1_kernel  <<<sbh,256,0,stream>>>(h1,h1,bsum,hlen);
  scanfix_kernel<<<sbh,256,0,stream>>>(h1,bsum,nullptr,sbh,hlen);
  scatter_kernel<8,0><<<SB,256,0,stream>>>(keysB,idxB,keysA,idxA,h1,
      nullptr,nullptr,nullptr,nullptr,nullptr, 8, N,nullptr,256,SB);
  // z pass 2
  hist_kernel<8><<<SB,256,0,stream>>>(keysA,h2,16,N,nullptr,256,SB);
  scan1_kernel  <<<sbh,256,0,stream>>>(h2,h2,bsum,hlen);
  scanfix_kernel<<<sbh,256,0,stream>>>(h2,bsum,nullptr,sbh,hlen);
  scatter_kernel<8,0><<<SB,256,0,stream>>>(keysA,idxA,keysB,idxB,h2,
      nullptr,nullptr,nullptr,nullptr,nullptr, 16, N,nullptr,256,SB);
  // z pass 3 (final: gather records into sorted order + tile counts)
  hist_kernel<8><<<SB,256,0,stream>>>(keysB,h3,24,N,nullptr,256,SB);
  scan1_kernel  <<<sbh,256,0,stream>>>(h3,h3,bsum,hlen);
  scanfix_kernel<<<sbh,256,0,stream>>>(h3,bsum,nullptr,sbh,hlen);
  scatter_kernel<8,1><<<SB,256,0,stream>>>(keysB,idxB,nullptr,nullptr,h3,
      xy,rec0,rxy,rec,ct, 24, N,nullptr,256,SB);

  // entry offsets per sorted gaussian + M
  int sbn=(N+1023)/1024;
  scan1_kernel  <<<sbn,256,0,stream>>>(ct,ct,bsum,N);
  scanfix_kernel<<<sbn,256,0,stream>>>(ct,bsum,Mptr,sbn,N);
  // emit entries (p-ascending, stable baseline)
  emit_kernel<<<SB,256,0,stream>>>(rxy,ct,entriesA,N);
  // tile pass A (low 8 bits of tile)
  hist_kernel<8><<<BT,256,0,stream>>>(entriesA,hT0,18,0,Mptr,ipbT,BT);
  int thlen=256*BT, sbt=(thlen+1023)/1024;
  scan1_kernel  <<<sbt,256,0,stream>>>(hT0,hT0,bsum,thlen);
  scanfix_kernel<<<sbt,256,0,stream>>>(hT0,bsum,nullptr,sbt,thlen);
  scatter_kernel<8,2><<<BT,256,0,stream>>>(entriesA,nullptr,entriesB,nullptr,hT0,
      nullptr,nullptr,nullptr,nullptr,nullptr, 18, 0,Mptr,ipbT,BT);
  // tile pass B (high 4 bits of tile)
  hist_kernel<4><<<BT,256,0,stream>>>(entriesB,hT1,26,0,Mptr,ipbT,BT);
  int t1len=16*BT, sb1=(t1len+1023)/1024;
  scan1_kernel  <<<sb1,256,0,stream>>>(hT1,hT1,bsum,t1len);
  scanfix_kernel<<<sb1,256,0,stream>>>(hT1,bsum,nullptr,sb1,t1len);
  scatter_kernel<4,2><<<BT,256,0,stream>>>(entriesB,nullptr,entriesA,nullptr,hT1,
      nullptr,nullptr,nullptr,nullptr,nullptr, 26, 0,Mptr,ipbT,BT);

  // tile boundaries + segment table
  tbound_kernel<<<(4*N)/256+1,256,0,stream>>>(entriesA,Mptr,tileoff);
  segscan_kernel<<<1,256,0,stream>>>(tileoff,segoff);

  // render
  renderseg_kernel<<<MAXSEGS,64,0,stream>>>(segoff,tileoff,entriesA,rec,pt);
  combine_kernel<<<NTILES,64,0,stream>>>(segoff,pt,(float*)d_out);
}

// Round 8
// 194.866 us; speedup vs baseline: 2.4179x; 1.0449x over previous
//
#include <hip/hip_runtime.h>
#include <hip/hip_fp16.h>
#include <stdint.h>

typedef uint32_t u32;
typedef uint64_t u64;

#define HWD 512
#define NTX 64            // 64x64 grid of 8x8 tiles
#define NTILES 4096
#define SEG 256           // entries per render segment
#define MAXSEGS 8192      // NTILES + 4N/SEG

__device__ __forceinline__ u32 packh2(float a, float b){
  __half2 h=__floats2half2_rn(a,b);
  return *reinterpret_cast<u32*>(&h);
}
__device__ __forceinline__ float2 unph2(u32 bits){
  __half2 h=*reinterpret_cast<__half2*>(&bits);
  return __half22float2(h);
}

// ---------------- prep: pose-inv + mask-probe + project/shade/pack + pass0 hist ----------------
__global__ void __launch_bounds__(256) prep_kernel(const float* __restrict__ pose,
    const float* __restrict__ means, const float* __restrict__ sh,
    const float* __restrict__ opac, const u32* __restrict__ maskw,
    u32* __restrict__ keys, u32* __restrict__ xy, float4* __restrict__ rec0,
    u32* __restrict__ h0, int N, int SB){
  __shared__ float pinvS[12];
  __shared__ u32 hh[256];
  __shared__ u32 mflag;
  int t=threadIdx.x, blk=blockIdx.x;
  int i=blk*256+t;
  hh[t]=0u;
  if (t<64){
    // mask dtype probe on first 64 words (uniform across blocks -> uniform decision)
    u32 w=maskw[t];
    bool isf=(w==0x3F800000u);
    bool ishi=((w&0xFFFFFF00u)!=0u)&&!isf;
    u64 bf=__ballot((int)isf), bh=__ballot((int)ishi);
    if (t==0) mflag = bh? 1u : (bf? 2u : 0u);   // 1=u8, 2=f32, 0=i32
  }
  if (t==0){
    double a[4][8];
    for(int r=0;r<4;r++)for(int c=0;c<4;c++){a[r][c]=(double)pose[r*4+c];a[r][4+c]=(r==c)?1.0:0.0;}
    for(int c=0;c<4;c++){
      int p=c;double best=fabs(a[c][c]);
      for(int r=c+1;r<4;r++){double v=fabs(a[r][c]);if(v>best){best=v;p=r;}}
      if(p!=c)for(int j=0;j<8;j++){double tt=a[c][j];a[c][j]=a[p][j];a[p][j]=tt;}
      double inv=1.0/a[c][c];
      for(int j=0;j<8;j++)a[c][j]*=inv;
      for(int r=0;r<4;r++)if(r!=c){double f=a[r][c];for(int j=0;j<8;j++)a[r][j]-=f*a[c][j];}
    }
    for(int r=0;r<3;r++)for(int c=0;c<4;c++) pinvS[r*4+c]=(float)a[r][4+c];
  }
  __syncthreads();
  if (i<N){
    u32 f=mflag;
    bool mk;
    if (f==1u)      mk=(((const unsigned char*)maskw)[i]!=0);
    else if (f==2u) mk=(((const float*)maskw)[i]!=0.0f);
    else            mk=(((const int*)maskw)[i]!=0);
    float x=means[3*i], y=means[3*i+1], z=means[3*i+2];
    float cx=pinvS[0]*x+pinvS[1]*y+pinvS[2]*z+pinvS[3];
    float cy=pinvS[4]*x+pinvS[5]*y+pinvS[6]*z+pinvS[7];
    float cz=pinvS[8]*x+pinvS[9]*y+pinvS[10]*z+pinvS[11];
    // exact op order of the reference: ((c*FX)/z) + CX, each fp32-rounded
    float x2d=(cx*409.6f)/cz; x2d=x2d+256.0f;
    float y2d=(cy*409.6f)/cz; y2d=y2d+256.0f;
    bool okx=(x2d>-1.0f)&&(x2d<512.0f);
    bool oky=(y2d>-1.0f)&&(y2d<512.0f);
    bool valid=mk&&okx&&oky;
    int xi=(int)x2d, yi=(int)y2d;
    float alpha= valid? opac[i]:0.0f;
    u32 pk= valid? ((u32)xi|((u32)yi<<16)) : 0xFFFFFFFFu;
    float c0=1.0f/(1.0f+expf(-sh[48*i]));
    float c1=1.0f/(1.0f+expf(-sh[48*i+16]));
    float c2=1.0f/(1.0f+expf(-sh[48*i+32]));
    u32 u=__float_as_uint(cz);
    u32 ou=u^(((u>>31)!=0u)?0xFFFFFFFFu:0x80000000u);
    u32 key=~ou;                    // ascending key == descending z
    keys[i]=key;
    xy[i]=pk;
    rec0[i]=make_float4(__uint_as_float(pk), c0, c1, __uint_as_float(packh2(c2,alpha)));
    atomicAdd(&hh[key&255u],1u);    // LDS only
  }
  __syncthreads();
  h0[t*SB+blk]=hh[t];
}

// ---------------- scan1: per-1024-window exclusive scan + window sums ----------------
__global__ void __launch_bounds__(256) scan1_kernel(const u32* __restrict__ in, u32* __restrict__ out,
                             u32* __restrict__ bsum, int len){
  __shared__ u32 s[256];
  int t=threadIdx.x, blk=blockIdx.x;
  int base=blk*1024 + t*4;
  u32 v0=(base+0<len)?in[base+0]:0u;
  u32 v1=(base+1<len)?in[base+1]:0u;
  u32 v2=(base+2<len)?in[base+2]:0u;
  u32 v3=(base+3<len)?in[base+3]:0u;
  s[t]=v0+v1+v2+v3; __syncthreads();
  for (int off=1;off<256;off<<=1){ u32 x=(t>=off)?s[t-off]:0u; __syncthreads(); s[t]+=x; __syncthreads(); }
  if (t==255) bsum[blk]=s[255];
  u32 run=(t==0)?0u:s[t-1];
  if (base+0<len) out[base+0]=run; run+=v0;
  if (base+1<len) out[base+1]=run; run+=v1;
  if (base+2<len) out[base+2]=run; run+=v2;
  if (base+3<len) out[base+3]=run;
}

// ---------------- per-block histogram (LDS atomics only, transposed write) ----------------
template<int NBITS>
__global__ void __launch_bounds__(256) hist_kernel(const u32* __restrict__ keys,
    u32* __restrict__ h, int shift, int n, const u32* __restrict__ nptr, int ipb, int B){
  constexpr int BINS=1<<NBITS;
  __shared__ u32 hh[BINS];
  int t=threadIdx.x, blk=blockIdx.x;
  for (int d=t; d<BINS; d+=256) hh[d]=0u;
  if (nptr) n=(int)*nptr;
  __syncthreads();
  int base=blk*ipb;
  for (int k=0;k<ipb;k+=256){
    int i=base+k+t;
    if (i<n) atomicAdd(&hh[(keys[i]>>shift)&(u32)(BINS-1)],1u);
  }
  __syncthreads();
  for (int d=t; d<BINS; d+=256) h[d*B+blk]=hh[d];
}

// ---------------- multi-wave stable radix scatter (fused global-prefix fixup) ----------------
// histS holds scan1's per-window exclusive scans; bsum holds the nW window sums.
// Each block scans bsum in LDS and adds gpre[(d*B+blk)>>10] itself (scanfix eliminated).
// MODE 0: key+payload scatter
// MODE 1: final z pass — gather packed records into sorted order + per-gaussian tile count
// MODE 2: key-only scatter
template<int NBITS, int MODE>
__global__ void __launch_bounds__(256) scatter_kernel(
    const u32* __restrict__ kin, const u32* __restrict__ pin,
    u32* __restrict__ kout, u32* __restrict__ pout,
    const u32* __restrict__ histS, const u32* __restrict__ bsum, int nW,
    const u32* __restrict__ xy, const float4* __restrict__ rec0,
    u32* __restrict__ rxy, float4* __restrict__ rec, u32* __restrict__ ct,
    int shift, int n, const u32* __restrict__ nptr, int ipb, int B){
  constexpr int BINS=1<<NBITS;
  __shared__ u32 base[BINS];
  __shared__ u32 wdc[4][BINS];
  __shared__ u32 gp[256];
  int t=threadIdx.x, w=t>>6, lane=t&63, blk=blockIdx.x;
  // scan window sums -> exclusive global prefixes
  u32 v=(t<nW)?bsum[t]:0u;
  gp[t]=v; __syncthreads();
  for (int off=1;off<256;off<<=1){ u32 x=(t>=off)?gp[t-off]:0u; __syncthreads(); gp[t]+=x; __syncthreads(); }
  u32 myex=(t==0)?0u:gp[t-1]; __syncthreads(); gp[t]=myex; __syncthreads();
  for (int d=t; d<BINS; d+=256){ u32 e=(u32)d*(u32)B+(u32)blk; base[d]=histS[e]+gp[e>>10]; }
  for (int d=t; d<4*BINS; d+=256) ((u32*)wdc)[d]=0u;
  if (nptr) n=(int)*nptr;
  __syncthreads();
  u64 lt=(1ull<<lane)-1ull;
  int nch=ipb>>8;
  for (int c=0;c<nch;c++){
    int i=blk*ipb + c*256 + t;
    bool live=(i<n);
    u32 key=live?kin[i]:0u;
    u32 pay=0u;
    if constexpr (MODE==0){ pay = pin? (live?pin[i]:0u) : (u32)i; }
    else if constexpr (MODE==1){ pay = live?pin[i]:0u; }
    u32 d=(key>>shift)&(u32)(BINS-1);
    u64 m=~0ull;
    #pragma unroll
    for (int b=0;b<NBITS;b++){ u64 bal=__ballot((int)((d>>b)&1u)); m &= ((d>>b)&1u)?bal:~bal; }
    m &= __ballot((int)live);
    u32 rank=(u32)__popcll(m&lt);
    u32 cnt=(u32)__popcll(m);
    if (live && rank==0u) wdc[w][d]=cnt;
    __syncthreads();
    if (live){
      u32 off=base[d]+rank;
      for (int w2=0;w2<w;w2++) off+=wdc[w2][d];
      if constexpr (MODE==0){
        kout[off]=key; pout[off]=pay;
      } else if constexpr (MODE==1){
        u32 pk=xy[pay];
        rxy[off]=pk;
        rec[off]=rec0[pay];
        u32 c2=0u;
        if (pk!=0xFFFFFFFFu){
          int xi=(int)(pk&0xFFFFu), yi=(int)(pk>>16);
          int tx0=max(xi-2,0)>>3, tx1=min(xi+2,HWD-1)>>3;
          int ty0=max(yi-2,0)>>3, ty1=min(yi+2,HWD-1)>>3;
          c2=(u32)((tx1-tx0+1)*(ty1-ty0+1));
        }
        ct[off]=c2;
      } else {
        kout[off]=key;
      }
    }
    __syncthreads();
    for (int d2=t; d2<BINS; d2+=256){
      base[d2]+=wdc[0][d2]+wdc[1][d2]+wdc[2][d2]+wdc[3][d2];
      wdc[0][d2]=0u; wdc[1][d2]=0u; wdc[2][d2]=0u; wdc[3][d2]=0u;
    }
    __syncthreads();
  }
}

// ---------------- emit: entries at scanned offsets (+ global prefix fixup + Mptr) ----------------
__global__ void __launch_bounds__(256) emit_kernel(const u32* __restrict__ rxy,
    const u32* __restrict__ coffs, const u32* __restrict__ bsum, int nW,
    u32* __restrict__ Mptr, u32* __restrict__ entries, int N){
  __shared__ u32 red[256];
  int t=threadIdx.x, blk=blockIdx.x;
  int w0=blk>>2;                 // 256-item block -> its 1024-window
  u32 s=0u;
  for (int j=t;j<w0;j+=256) s+=bsum[j];
  red[t]=s; __syncthreads();
  for (int off=128;off>0;off>>=1){ if(t<off) red[t]+=red[t+off]; __syncthreads(); }
  u32 gpre=red[0];
  if (blk==0){
    __syncthreads();
    u32 s2=0u;
    for (int j=t;j<nW;j+=256) s2+=bsum[j];
    red[t]=s2; __syncthreads();
    for (int off=128;off>0;off>>=1){ if(t<off) red[t]+=red[t+off]; __syncthreads(); }
    if (t==0) *Mptr=red[0];
  }
  int p=blk*256+t; if(p>=N) return;
  u32 pk=rxy[p]; if(pk==0xFFFFFFFFu) return;
  int xi=(int)(pk&0xFFFFu), yi=(int)(pk>>16);
  int tx0=max(xi-2,0)>>3, tx1=min(xi+2,HWD-1)>>3;
  int ty0=max(yi-2,0)>>3, ty1=min(yi+2,HWD-1)>>3;
  u32 o=coffs[p]+gpre;
  for (int ty=ty0;ty<=ty1;ty++)
    for (int tx=tx0;tx<=tx1;tx++){
      entries[o]=((u32)(ty*NTX+tx)<<18)|(u32)p;
      o++;
    }
}

// ---------------- tile boundaries from sorted entries ----------------
__global__ void __launch_bounds__(256) tbound_kernel(const u32* __restrict__ entries,
    const u32* __restrict__ Mptr, u32* __restrict__ tileoff){
  u32 M=*Mptr;
  u32 i=(u32)blockIdx.x*256u+(u32)threadIdx.x;
  if (i>M) return;
  if (i==M){
    int tlast=(M==0u)? -1 : (int)(entries[M-1]>>18);
    for (int tt=tlast+1; tt<=NTILES; tt++) tileoff[tt]=M;
    return;
  }
  int ti=(int)(entries[i]>>18);
  int tp=(i==0u)? -1 : (int)(entries[i-1]>>18);
  for (int tt=tp+1; tt<=ti; tt++) tileoff[tt]=i;
}

// ---------------- segment table from tileoff (single block) ----------------
__global__ void __launch_bounds__(256) segscan_kernel(const u32* __restrict__ tileoff,
    u32* __restrict__ segoff){
  __shared__ u32 s[256];
  int t=threadIdx.x;
  u32 pseg[16]; u32 ssum=0u;
  #pragma unroll
  for (int k=0;k<16;k++){
    int tile=t*16+k;
    u32 cnt=tileoff[tile+1]-tileoff[tile];
    pseg[k]=ssum; ssum+=(cnt+SEG-1)/SEG;
  }
  s[t]=ssum; __syncthreads();
  for (int off=1;off<256;off<<=1){ u32 x=(t>=off)?s[t-off]:0u; __syncthreads(); s[t]+=x; __syncthreads(); }
  u32 b2=(t==0)?0u:s[t-1];
  #pragma unroll
  for (int k=0;k<16;k++) segoff[t*16+k]=b2+pseg[k];
  if (t==255) segoff[NTILES]=s[255];
}

// ---------------- render phase 1: 4 waves/block, one 256-entry segment per wave ----------------
// Wave-private LDS staging + wave_barrier only (no __syncthreads) — pattern verified r2/r3.
__global__ void __launch_bounds__(256) renderseg_kernel(const u32* __restrict__ segoff,
    const u32* __restrict__ tileoff, const u32* __restrict__ sidE,
    const float4* __restrict__ rec, float4* __restrict__ pt){
  __shared__ float4 sac[4][64];
  int t=threadIdx.x, w=t>>6, lane=t&63;
  u32 k=(u32)blockIdx.x*4u+(u32)w;
  u32 nseg=segoff[NTILES];
  if (k>=nseg) return;
  int lo=0, hi=NTILES-1;
  while (lo<hi){ int mid=(lo+hi+1)>>1; if (segoff[mid]<=k) lo=mid; else hi=mid-1; }
  int tile=lo;
  u32 st=tileoff[tile], en=tileoff[tile+1];
  int s0=(int)st+(int)(k-segoff[tile])*SEG;
  int s1=min(s0+SEG,(int)en);
  int px=(tile&(NTX-1))*8+(lane&7), py=(tile/NTX)*8+(lane>>3);
  float T=1.0f, cr=0.0f, cg=0.0f, cb=0.0f;
  for (int base=s0;base<s1;base+=64){
    int i=base+lane;
    if (i<s1) sac[w][lane]=rec[sidE[i]&0x3FFFFu];
    __builtin_amdgcn_wave_barrier();
    int cnt=min(64,s1-base);
    int j=0;
    for (;j+4<=cnt;j+=4){
      #pragma unroll
      for (int q=0;q<4;q++){
        float4 R=sac[w][j+q];
        u32 pk=__float_as_uint(R.x);
        int dx=px-(int)(pk&0xFFFFu);
        int dy=py-(int)(pk>>16);
        int r2=dx*dx+dy*dy;
        float2 ca=unph2(__float_as_uint(R.w));   // (c2, alpha)
        float aw=ca.y*exp2f(-0.72134752f*(float)r2);
        aw=(r2<=8)?aw:0.0f;
        float om=1.0f-aw;
        T*=om;
        cr=om*cr+aw*R.y;
        cg=om*cg+aw*R.z;
        cb=om*cb+aw*ca.x;
      }
    }
    for (;j<cnt;j++){
      float4 R=sac[w][j];
      u32 pk=__float_as_uint(R.x);
      int dx=px-(int)(pk&0xFFFFu);
      int dy=py-(int)(pk>>16);
      int r2=dx*dx+dy*dy;
      float2 ca=unph2(__float_as_uint(R.w));
      float aw=ca.y*exp2f(-0.72134752f*(float)r2);
      aw=(r2<=8)?aw:0.0f;
      float om=1.0f-aw;
      T*=om;
      cr=om*cr+aw*R.y;
      cg=om*cg+aw*R.z;
      cb=om*cb+aw*ca.x;
    }
    __builtin_amdgcn_wave_barrier();
  }
  pt[k*64u+(u32)lane]=make_float4(T,cr,cg,cb);
}

// ---------------- render phase 2: compose segment maps in depth order ----------------
__global__ void __launch_bounds__(64) combine_kernel(const u32* __restrict__ segoff,
    const float4* __restrict__ pt, float* __restrict__ out){
  int tile=blockIdx.x, lane=threadIdx.x;
  u32 a=segoff[tile], b=segoff[tile+1];
  float cr=0.0f,cg=0.0f,cb=0.0f;
  for (u32 s=a;s<b;s++){
    float4 P=pt[s*64u+(u32)lane];
    cr=P.x*cr+P.y; cg=P.x*cg+P.z; cb=P.x*cb+P.w;
  }
  int px=(tile&(NTX-1))*8+(lane&7), py=(tile/NTX)*8+(lane>>3);
  int o=py*HWD+px;
  out[o]=cr; out[HWD*HWD+o]=cg; out[2*HWD*HWD+o]=cb;
}

// ---------------- launcher ----------------
extern "C" void kernel_launch(void* const* d_in, const int* in_sizes, int n_in,
                              void* d_out, int out_size, void* d_ws, size_t ws_size,
                              hipStream_t stream){
  const float* pose=(const float*)d_in[0];
  const float* means=(const float*)d_in[1];
  const float* sh=(const float*)d_in[2];
  const float* opac=(const float*)d_in[3];
  const u32* maskw=(const u32*)d_in[4];
  int N=in_sizes[4];
  if (N<=0) return;
  (void)n_in; (void)out_size; (void)ws_size;

  int SB=(N+255)/256;                    // z-sort blocks (ipb=256)
  const int BT=1024;                     // tile-sort blocks
  int Llog=8; while ((BT<<Llog) < 4*N) Llog++;
  int ipbT=1<<Llog;

  char* ws=(char*)d_ws; size_t off=0;
  auto alloc=[&](size_t b)->void*{ void* p=(void*)(ws+off); off=(off+b+255)&~(size_t)255; return p; };
  u32* keysA=(u32*)alloc(4ull*N);
  u32* keysB=(u32*)alloc(4ull*N);
  u32* idxA =(u32*)alloc(4ull*N);
  u32* idxB =(u32*)alloc(4ull*N);
  u32* xy   =(u32*)alloc(4ull*N);
  float4* rec0=(float4*)alloc(16ull*N);
  u32* rxy  =(u32*)alloc(4ull*N);
  float4* rec=(float4*)alloc(16ull*N);
  u32* ct   =(u32*)alloc(4ull*N);
  u32* entriesA=(u32*)alloc(4ull*4*N);   // also final sorted entries
  u32* entriesB=(u32*)alloc(4ull*4*N);
  u32* h0=(u32*)alloc(1024ull*SB);
  u32* h1=(u32*)alloc(1024ull*SB);
  u32* h2=(u32*)alloc(1024ull*SB);
  u32* h3=(u32*)alloc(1024ull*SB);
  u32* hT0=(u32*)alloc(4ull*256*BT);
  u32* hT1=(u32*)alloc(4ull*16*BT);
  u32* tileoff=(u32*)alloc(4ull*(NTILES+1));
  u32* segoff =(u32*)alloc(4ull*(NTILES+1));
  u32* bsum=(u32*)alloc(4ull*4096);
  u32* Mptr=(u32*)alloc(256);
  float4* pt=(float4*)alloc(16ull*64*MAXSEGS);   // 8 MB

  hipMemsetAsync(tileoff,0,4ull*(NTILES+1),stream);
  prep_kernel<<<SB,256,0,stream>>>(pose,means,sh,opac,maskw,keysA,xy,rec0,h0,N,SB);

  int hlen=256*SB, sbh=(hlen+1023)/1024;          // = 256 windows
  int nWz=sbh;
  // z pass 0
  scan1_kernel<<<sbh,256,0,stream>>>(h0,h0,bsum,hlen);
  scatter_kernel<8,0><<<SB,256,0,stream>>>(keysA,nullptr,keysB,idxB,h0,bsum,nWz,
      nullptr,nullptr,nullptr,nullptr,nullptr, 0, N,nullptr,256,SB);
  // z pass 1
  hist_kernel<8><<<SB,256,0,stream>>>(keysB,h1,8,N,nullptr,256,SB);
  scan1_kernel<<<sbh,256,0,stream>>>(h1,h1,bsum,hlen);
  scatter_kernel<8,0><<<SB,256,0,stream>>>(keysB,idxB,keysA,idxA,h1,bsum,nWz,
      nullptr,nullptr,nullptr,nullptr,nullptr, 8, N,nullptr,256,SB);
  // z pass 2
  hist_kernel<8><<<SB,256,0,stream>>>(keysA,h2,16,N,nullptr,256,SB);
  scan1_kernel<<<sbh,256,0,stream>>>(h2,h2,bsum,hlen);
  scatter_kernel<8,0><<<SB,256,0,stream>>>(keysA,idxA,keysB,idxB,h2,bsum,nWz,
      nullptr,nullptr,nullptr,nullptr,nullptr, 16, N,nullptr,256,SB);
  // z pass 3 (final: gather records into sorted order + tile counts)
  hist_kernel<8><<<SB,256,0,stream>>>(keysB,h3,24,N,nullptr,256,SB);
  scan1_kernel<<<sbh,256,0,stream>>>(h3,h3,bsum,hlen);
  scatter_kernel<8,1><<<SB,256,0,stream>>>(keysB,idxB,nullptr,nullptr,h3,bsum,nWz,
      xy,rec0,rxy,rec,ct, 24, N,nullptr,256,SB);

  // entry offsets per sorted gaussian (windowed scan; emit adds global prefix + writes M)
  int sbn=(N+1023)/1024;
  scan1_kernel<<<sbn,256,0,stream>>>(ct,ct,bsum,N);
  emit_kernel<<<SB,256,0,stream>>>(rxy,ct,bsum,sbn,Mptr,entriesA,N);
  // tile pass A (low 8 bits of tile)
  hist_kernel<8><<<BT,256,0,stream>>>(entriesA,hT0,18,0,Mptr,ipbT,BT);
  int thlen=256*BT, sbt=(thlen+1023)/1024;
  scan1_kernel<<<sbt,256,0,stream>>>(hT0,hT0,bsum,thlen);
  scatter_kernel<8,2><<<BT,256,0,stream>>>(entriesA,nullptr,entriesB,nullptr,hT0,bsum,sbt,
      nullptr,nullptr,nullptr,nullptr,nullptr, 18, 0,Mptr,ipbT,BT);
  // tile pass B (high 4 bits of tile)
  hist_kernel<4><<<BT,256,0,stream>>>(entriesB,hT1,26,0,Mptr,ipbT,BT);
  int t1len=16*BT, sb1=(t1len+1023)/1024;
  scan1_kernel<<<sb1,256,0,stream>>>(hT1,hT1,bsum,t1len);
  scatter_kernel<4,2><<<BT,256,0,stream>>>(entriesB,nullptr,entriesA,nullptr,hT1,bsum,sb1,
      nullptr,nullptr,nullptr,nullptr,nullptr, 26, 0,Mptr,ipbT,BT);

  // tile boundaries + segment table
  tbound_kernel<<<(4*N)/256+1,256,0,stream>>>(entriesA,Mptr,tileoff);
  segscan_kernel<<<1,256,0,stream>>>(tileoff,segoff);

  // render (4 segments per 256-thread block, one per wave)
  renderseg_kernel<<<(MAXSEGS+3)/4,256,0,stream>>>(segoff,tileoff,entriesA,rec,pt);
  combine_kernel<<<NTILES,64,0,stream>>>(segoff,pt,(float*)d_out);
}